// Round 5
// baseline (56410.229 us; speedup 1.0000x reference)
//
#include <hip/hip_runtime.h>
#include <math.h>

#define BDIM   262144
#define IN_DIM 54
#define HID    256
#define EXPD   512
#define LAT    32
#define NBLK   4
#define NCODES 512
#define EPS    1e-5

// d_out layout (floats): x_recon | z_q_st | indices | commit_loss
#define O_ZQ   14155776
#define O_IDX  22544384
#define O_LOSS 22806528

#define AST 260     // A row stride (floats); rows 1040B, float4-aligned

template<typename T> __device__ __forceinline__ T gelu_T(T x);
template<> __device__ __forceinline__ double gelu_T<double>(double x) {
    return 0.5 * x * (1.0 + erf(x * 0.70710678118654752440));
}
template<> __device__ __forceinline__ float gelu_T<float>(float x) {
    return 0.5f * x * (1.0f + erff(x * 0.70710678f));
}
template<typename T> __device__ __forceinline__ T rsqrt_T(T x);
template<> __device__ __forceinline__ double rsqrt_T<double>(double x) { return 1.0 / sqrt(x); }
template<> __device__ __forceinline__ float  rsqrt_T<float>(float x)  { return 1.0f / sqrtf(x); }

// ---------------------------------------------------------------------------
// LayerNorm: acc[4][4] (rows rt*4+i, cols ct*4+j) -> normalized f32 into A
// row-major [16][AST] (b128 contiguous writes, conflict-free). Wave-local
// shfl reduction (wave rt owns rows rt*4..+3). If b2: preload residual bias.
// ---------------------------------------------------------------------------
template<typename T>
__device__ __forceinline__ void ln_write_A(T acc[4][4], float* A,
    const float* __restrict__ g, const float* __restrict__ bta,
    const float* __restrict__ b2, int rt, int ct)
{
    T s[4], sq[4];
    #pragma unroll
    for (int i = 0; i < 4; i++) {
        s[i]  = acc[i][0] + acc[i][1] + acc[i][2] + acc[i][3];
        sq[i] = acc[i][0]*acc[i][0] + acc[i][1]*acc[i][1]
              + acc[i][2]*acc[i][2] + acc[i][3]*acc[i][3];
    }
    #pragma unroll
    for (int m = 1; m < 64; m <<= 1) {
        #pragma unroll
        for (int i = 0; i < 4; i++) {
            s[i]  += __shfl_xor(s[i],  m);
            sq[i] += __shfl_xor(sq[i], m);
        }
    }
    float4 gv = *(const float4*)(g + ct*4);
    float4 bv = *(const float4*)(bta + ct*4);
    float gj[4] = {gv.x, gv.y, gv.z, gv.w};
    float bj[4] = {bv.x, bv.y, bv.z, bv.w};
    #pragma unroll
    for (int i = 0; i < 4; i++) {
        T mu  = s[i]  * (T)(1.0 / HID);
        T var = sq[i] * (T)(1.0 / HID) - mu * mu;
        T rs  = rsqrt_T<T>(var + (T)EPS);
        float4 o;
        o.x = (float)((acc[i][0] - mu) * rs * (T)gj[0] + (T)bj[0]);
        o.y = (float)((acc[i][1] - mu) * rs * (T)gj[1] + (T)bj[1]);
        o.z = (float)((acc[i][2] - mu) * rs * (T)gj[2] + (T)bj[2]);
        o.w = (float)((acc[i][3] - mu) * rs * (T)gj[3] + (T)bj[3]);
        *(float4*)(A + (rt*4 + i)*AST + ct*4) = o;
    }
    if (b2) {
        float4 b2v = *(const float4*)(b2 + ct*4);
        float bb[4] = {b2v.x, b2v.y, b2v.z, b2v.w};
        #pragma unroll
        for (int i = 0; i < 4; i++)
            #pragma unroll
            for (int j = 0; j < 4; j++)
                acc[i][j] += (T)bb[j];
    }
}

// ---------------------------------------------------------------------------
// A(LDS, broadcast) x W(global, slab-staged): acc[4][4] += A[.][k] @ W[k][256]
// W row k at W + k*rowPitch (256 cols used). Slab SR rows x 256 cols, register
// relay prefetch (loads for slab s+1 issued before computing slab s).
// ---------------------------------------------------------------------------
template<typename T, int SR>
__device__ __forceinline__ void gemm_als(T acc[4][4], const float* A,
    const float* __restrict__ W, long rowPitch, int totRows,
    float* slab, int rt, int ct, int tid)
{
    float4 R[SR/4];
    {
        int n0 = totRows < SR ? totRows : SR;
        #pragma unroll
        for (int u = 0; u < SR/4; u++) {
            int idx = tid + 256*u, row = idx >> 6;
            if (row < n0) R[u] = *(const float4*)(W + (long)row*rowPitch + (idx & 63)*4);
        }
    }
    for (int k0 = 0; k0 < totRows; k0 += SR) {
        int n = totRows - k0; if (n > SR) n = SR;
        __syncthreads();
        #pragma unroll
        for (int u = 0; u < SR/4; u++) {
            int idx = tid + 256*u;
            if ((idx >> 6) < n) *(float4*)(slab + idx*4) = R[u];
        }
        __syncthreads();
        if (k0 + SR < totRows) {
            int n2 = totRows - k0 - SR; if (n2 > SR) n2 = SR;
            const float* src = W + (long)(k0 + SR)*rowPitch;
            #pragma unroll
            for (int u = 0; u < SR/4; u++) {
                int idx = tid + 256*u, row = idx >> 6;
                if (row < n2) R[u] = *(const float4*)(src + (long)row*rowPitch + (idx & 63)*4);
            }
        }
        #pragma unroll 2
        for (int k = 0; k < n; k++) {
            T a[4];
            #pragma unroll
            for (int i = 0; i < 4; i++) a[i] = (T)A[(rt*4 + i)*AST + k0 + k];  // broadcast
            float4 wv = *(const float4*)(slab + k*256 + ct*4);                  // contiguous
            T w[4] = {(T)wv.x, (T)wv.y, (T)wv.z, (T)wv.w};
            #pragma unroll
            for (int i = 0; i < 4; i++)
                #pragma unroll
                for (int j = 0; j < 4; j++)
                    acc[i][j] += a[i] * w[j];
        }
    }
}

// ---------------------------------------------------------------------------
// GEMM2 half: acc[4][4] += y(registers, shfl-broadcast) @ W2h[256][256]
// y rows rt*4..+3 live within wave rt: y[row rt*4+i][h*256 + lane*4+sub]
// is yreg[i][sub] of lane `lane`. Register index sub is compile-time.
// ---------------------------------------------------------------------------
template<typename T, int SR>
__device__ __forceinline__ void gemm2_shfl(T acc[4][4], T yreg[4][4],
    const float* __restrict__ W2h, float* slab, int ct, int tid)
{
    float4 R[SR/4];
    #pragma unroll
    for (int u = 0; u < SR/4; u++)
        R[u] = *(const float4*)(W2h + (tid + 256*u)*4);      // rows contiguous (pitch 256)
    for (int e0 = 0; e0 < 256; e0 += SR) {
        __syncthreads();
        #pragma unroll
        for (int u = 0; u < SR/4; u++)
            *(float4*)(slab + (tid + 256*u)*4) = R[u];
        __syncthreads();
        if (e0 + SR < 256) {
            const float* src = W2h + (long)(e0 + SR)*256;
            #pragma unroll
            for (int u = 0; u < SR/4; u++)
                R[u] = *(const float4*)(src + (tid + 256*u)*4);
        }
        #pragma unroll 1
        for (int eb = 0; eb < SR/4; eb++) {
            int lane = (e0 >> 2) + eb;
            #pragma unroll
            for (int sub = 0; sub < 4; sub++) {
                T yv[4];
                #pragma unroll
                for (int i = 0; i < 4; i++) yv[i] = __shfl(yreg[i][sub], lane);
                float4 wv = *(const float4*)(slab + (eb*4 + sub)*256 + ct*4);
                T w[4] = {(T)wv.x, (T)wv.y, (T)wv.z, (T)wv.w};
                #pragma unroll
                for (int i = 0; i < 4; i++)
                    #pragma unroll
                    for (int j = 0; j < 4; j++)
                        acc[i][j] += yv[i] * w[j];
            }
        }
    }
}

// ---------------------------------------------------------------------------
// One residual FFN block: acc = acc + gelu(LN(acc) @ W1 + b1) @ W2 + b2
// ---------------------------------------------------------------------------
template<typename T, int SR>
__device__ __forceinline__ void ffn_layer(T acc[4][4], float* A, float* slab,
    const float* lng, const float* lnb,
    const float* __restrict__ W1, const float* __restrict__ b1,
    const float* __restrict__ W2, const float* __restrict__ b2,
    int rt, int ct, int tid)
{
    ln_write_A<T>(acc, A, lng, lnb, b2, rt, ct);
    #pragma unroll 1
    for (int h = 0; h < 2; h++) {
        T yac[4][4] = {};
        gemm_als<T, SR>(yac, A, W1 + h*256, EXPD, HID, slab, rt, ct, tid);
        float4 b1v = *(const float4*)(b1 + h*256 + ct*4);
        float bb[4] = {b1v.x, b1v.y, b1v.z, b1v.w};
        T yreg[4][4];
        #pragma unroll
        for (int i = 0; i < 4; i++)
            #pragma unroll
            for (int j = 0; j < 4; j++)
                yreg[i][j] = gelu_T<T>(yac[i][j] + (T)bb[j]);
        gemm2_shfl<T, SR>(acc, yreg, W2 + (long)h*256*HID, slab, ct, tid);
    }
}

// ---------------------------------------------------------------------------
// Encoder megakernel (f64 acc, f32 LDS): x -> proj -> 4 blocks -> LN -> lat
// -> VQ -> z_q/idx/loss.  16 rows per workgroup.
// ---------------------------------------------------------------------------
__global__ __launch_bounds__(256, 2)
void k_encoder(const float* __restrict__ x,
               const float* __restrict__ epw, const float* __restrict__ epb,
               const float* __restrict__ lng, const float* __restrict__ lnb,
               const float* __restrict__ W1, const float* __restrict__ b1,
               const float* __restrict__ W2, const float* __restrict__ b2,
               const float* __restrict__ ng, const float* __restrict__ nb,
               const float* __restrict__ Wl, const float* __restrict__ bl,
               const float* __restrict__ cb, float* __restrict__ dout)
{
    typedef double T;
    __shared__ __align__(16) float A[16 * AST];     // 16640 B
    __shared__ __align__(16) float slab[8192];      // 32768 B
    const int tid = threadIdx.x;
    const int rt = tid >> 6, ct = tid & 63;
    const long row0 = (long)blockIdx.x * 16;

    // stage x rows [16][54] into A
    #pragma unroll
    for (int u = 0; u < 4; u++) {
        int idx = tid + 256*u;
        if (idx < 16 * IN_DIM)
            A[(idx / IN_DIM)*AST + (idx % IN_DIM)] = x[row0*IN_DIM + idx];
    }
    T acc[4][4];
    {
        float4 bv = *(const float4*)(epb + ct*4);
        float bb[4] = {bv.x, bv.y, bv.z, bv.w};
        #pragma unroll
        for (int i = 0; i < 4; i++)
            #pragma unroll
            for (int j = 0; j < 4; j++) acc[i][j] = (T)bb[j];
    }
    gemm_als<T, 32>(acc, A, epw, HID, IN_DIM, slab, rt, ct, tid);

    for (int l = 0; l < NBLK; l++)
        ffn_layer<T, 32>(acc, A, slab, lng + l*HID, lnb + l*HID,
                         W1 + (long)l*HID*EXPD, b1 + l*EXPD,
                         W2 + (long)l*EXPD*HID, b2 + l*HID, rt, ct, tid);

    ln_write_A<T>(acc, A, ng, nb, nullptr, rt, ct);

    // stage Wl [256][32] into slab (32 KB exactly)
    __syncthreads();
    #pragma unroll
    for (int u = 0; u < 8; u++)
        ((float4*)slab)[tid + 256*u] = *(const float4*)(Wl + (tid + 256*u)*4);
    __syncthreads();

    // latent projection (f64), thread map (r2, q2)
    const int r2 = tid >> 4, q2 = tid & 15;
    double z0, z1;
    {
        float2 blv = *(const float2*)(bl + q2*2);
        z0 = (double)blv.x; z1 = (double)blv.y;
        #pragma unroll 2
        for (int k = 0; k < HID; k++) {
            double a = (double)A[r2*AST + k];          // broadcast
            z0 += a * (double)slab[k*LAT + q2*2];
            z1 += a * (double)slab[k*LAT + q2*2 + 1];
        }
    }
    __syncthreads();                                   // slab (Wl) reads done
    double* ccs  = (double*)slab;                      // [0, 4096)
    double* zbuf = (double*)slab + NCODES;             // [4096, 8448)
    double* wsum = (double*)slab + 2000;               // [16000, 16032)
    zbuf[r2*34 + q2*2] = z0; zbuf[r2*34 + q2*2 + 1] = z1;
    #pragma unroll
    for (int u = 0; u < 2; u++) {
        int c = tid*2 + u;
        const float* cp = cb + (long)c * LAT;
        double sc = 0;
        #pragma unroll
        for (int j = 0; j < LAT; j += 4) {
            float4 v = *(const float4*)(cp + j);
            sc += (double)v.x*(double)v.x + (double)v.y*(double)v.y
                + (double)v.z*(double)v.z + (double)v.w*(double)v.w;
        }
        ccs[c] = sc;
    }
    __syncthreads();

    // VQ: thread (r2,q2) scans codes q2*32 .. q2*32+31
    double bd; int bi;
    {
        double zr[32];
        #pragma unroll
        for (int j = 0; j < LAT; j++) zr[j] = zbuf[r2*34 + j];
        double zz = 0;
        #pragma unroll
        for (int j = 0; j < LAT; j++) zz += zr[j]*zr[j];
        bd = 1e300; bi = 0;
        for (int c0 = 0; c0 < 32; c0++) {
            int code = q2*32 + c0;
            const float* cp = cb + (long)code * LAT;
            double dot = 0;
            #pragma unroll
            for (int j = 0; j < LAT; j += 4) {
                float4 v = *(const float4*)(cp + j);
                dot += zr[j]*(double)v.x + zr[j+1]*(double)v.y
                     + zr[j+2]*(double)v.z + zr[j+3]*(double)v.w;
            }
            double d2 = (zz - 2.0*dot) + ccs[code];
            if (d2 < bd) { bd = d2; bi = code; }       // strict <: first-min
        }
        #pragma unroll
        for (int m = 1; m < 16; m <<= 1) {
            double ob = __shfl_xor(bd, m);
            int   obi = __shfl_xor(bi, m);
            if (ob < bd || (ob == bd && obi < bi)) { bd = ob; bi = obi; }
        }
        if (q2 == 0) {
            long grow = row0 + r2;
            dout[O_IDX + grow] = (float)bi;
            const float* cq = cb + (long)bi * LAT;
            #pragma unroll
            for (int j = 0; j < LAT; j += 4)
                *(float4*)(dout + O_ZQ + grow*LAT + j) = *(const float4*)(cq + j);
        }
    }
    // commit loss: wave sums -> block sum -> one atomic
    double ws = bd;
    ws += __shfl_xor(ws, 16);
    ws += __shfl_xor(ws, 32);
    if ((tid & 63) == 0) wsum[tid >> 6] = ws;
    __syncthreads();
    if (tid == 0)
        atomicAdd(dout + O_LOSS, (float)(wsum[0] + wsum[1] + wsum[2] + wsum[3]));
}

// ---------------------------------------------------------------------------
// Decoder megakernel (f32): z_q -> lat -> 4 blocks -> LN -> proj -> x_recon
// ---------------------------------------------------------------------------
__global__ __launch_bounds__(256, 4)
void k_decoder(float* __restrict__ dout,
               const float* __restrict__ Wl, const float* __restrict__ bl,
               const float* __restrict__ lng, const float* __restrict__ lnb,
               const float* __restrict__ W1, const float* __restrict__ b1,
               const float* __restrict__ W2, const float* __restrict__ b2,
               const float* __restrict__ ng, const float* __restrict__ nb,
               const float* __restrict__ Wp, const float* __restrict__ pb)
{
    typedef float T;
    __shared__ __align__(16) float A[16 * AST];
    __shared__ __align__(16) float slab[8192];
    const int tid = threadIdx.x;
    const int rt = tid >> 6, ct = tid & 63;
    const long row0 = (long)blockIdx.x * 16;

    // stage z_q [16][32] into A
    #pragma unroll
    for (int u = 0; u < 2; u++) {
        int idx = tid + 256*u;                 // < 512
        A[(idx >> 5)*AST + (idx & 31)] = dout[O_ZQ + row0*LAT + idx];
    }
    T acc[4][4];
    {
        float4 bv = *(const float4*)(bl + ct*4);
        float bb[4] = {bv.x, bv.y, bv.z, bv.w};
        #pragma unroll
        for (int i = 0; i < 4; i++)
            #pragma unroll
            for (int j = 0; j < 4; j++) acc[i][j] = bb[j];
    }
    gemm_als<T, 32>(acc, A, Wl, HID, LAT, slab, rt, ct, tid);

    for (int l = 0; l < NBLK; l++)
        ffn_layer<T, 32>(acc, A, slab, lng + l*HID, lnb + l*HID,
                         W1 + (long)l*HID*EXPD, b1 + l*EXPD,
                         W2 + (long)l*EXPD*HID, b2 + l*HID, rt, ct, tid);

    ln_write_A<T>(acc, A, ng, nb, nullptr, rt, ct);

    // output projection: k-chunks of 64 rows of Wp [256][54] staged in slab
    const int r2 = tid >> 4, q2 = tid & 15;
    float oacc[4];
    #pragma unroll
    for (int j = 0; j < 4; j++) {
        int c = q2*4 + j;
        oacc[j] = (c < IN_DIM) ? pb[c] : 0.f;
    }
    for (int k0 = 0; k0 < HID; k0 += 64) {
        __syncthreads();
        #pragma unroll
        for (int u = 0; u < 4; u++) {
            int idx = tid + 256*u;
            if (idx < 864)                       // 64*54/4 float4s
                ((float4*)slab)[idx] = *(const float4*)(Wp + (long)k0*IN_DIM + idx*4);
        }
        __syncthreads();
        #pragma unroll 2
        for (int k = 0; k < 64; k++) {
            float a = A[r2*AST + k0 + k];        // broadcast
            #pragma unroll
            for (int j = 0; j < 4; j++)
                oacc[j] += a * slab[k*IN_DIM + q2*4 + j];   // c>=54 reads harmless garbage
        }
    }
    #pragma unroll
    for (int j = 0; j < 4; j++) {
        int c = q2*4 + j;
        if (c < IN_DIM) dout[(row0 + r2)*IN_DIM + c] = oacc[j];
    }
}

__global__ void k_zero(float* p) { *p = 0.0f; }
__global__ void k_final(float* p) { *p = *p * (1.0f / 8388608.0f); }  // / (B*LAT) = 2^-23, exact

// ---------------------------------------------------------------------------
extern "C" void kernel_launch(void* const* d_in, const int* in_sizes, int n_in,
                              void* d_out, int out_size, void* d_ws, size_t ws_size,
                              hipStream_t stream)
{
    (void)in_sizes; (void)n_in; (void)out_size; (void)d_ws; (void)ws_size;
    const float* x     = (const float*)d_in[0];
    const float* epw   = (const float*)d_in[1];
    const float* epb   = (const float*)d_in[2];
    const float* elng  = (const float*)d_in[3];
    const float* elnb  = (const float*)d_in[4];
    const float* ew1   = (const float*)d_in[5];
    const float* eb1   = (const float*)d_in[6];
    const float* ew2   = (const float*)d_in[7];
    const float* eb2   = (const float*)d_in[8];
    const float* eng   = (const float*)d_in[9];
    const float* enb   = (const float*)d_in[10];
    const float* elatw = (const float*)d_in[11];
    const float* elatb = (const float*)d_in[12];
    const float* cbk   = (const float*)d_in[13];
    const float* dlatw = (const float*)d_in[14];
    const float* dlatb = (const float*)d_in[15];
    const float* dlng  = (const float*)d_in[16];
    const float* dlnb  = (const float*)d_in[17];
    const float* dw1   = (const float*)d_in[18];
    const float* db1   = (const float*)d_in[19];
    const float* dw2   = (const float*)d_in[20];
    const float* db2   = (const float*)d_in[21];
    const float* dng   = (const float*)d_in[22];
    const float* dnb   = (const float*)d_in[23];
    const float* dpw   = (const float*)d_in[24];
    const float* dpb   = (const float*)d_in[25];
    float* out = (float*)d_out;

    dim3 blk(256, 1, 1);
    k_zero<<<1, 1, 0, stream>>>(out + O_LOSS);
    k_encoder<<<BDIM / 16, blk, 0, stream>>>(
        x, epw, epb, elng, elnb, ew1, eb1, ew2, eb2, eng, enb, elatw, elatb, cbk, out);
    k_decoder<<<BDIM / 16, blk, 0, stream>>>(
        out, dlatw, dlatb, dlng, dlnb, dw1, db1, dw2, db2, dng, dnb, dpw, dpb);
    k_final<<<1, 1, 0, stream>>>(out + O_LOSS);
}